// Round 1
// baseline (149.473 us; speedup 1.0000x reference)
//
#include <hip/hip_runtime.h>

// Problem constants (fixed by the reference)
#define BATCH   128
#define C_IN    3
#define C_OUT   16
#define HW      65536                 // 256*256
#define PLANES  (BATCH * C_IN)        // 384
#define BPP     4                     // blocks per plane (load balance: 1536 blocks / 256 CUs)
#define NBLK    (PLANES * BPP)        // 1536
#define F4_PER_PLANE 16384            // HW/4
#define F4_PER_BLOCK (F4_PER_PLANE / BPP)   // 4096
#define THREADS 256

// Kernel 1: partial plane sums. Each block reduces a contiguous quarter of one
// (b, ci) plane with float4 loads (16 B/lane coalesced), wave-shuffle + LDS
// tree reduction, one partial per block.
__global__ __launch_bounds__(THREADS) void plane_partials(
        const float* __restrict__ x, float* __restrict__ part) {
    const float4* xp = (const float4*)x + (size_t)blockIdx.x * F4_PER_BLOCK;
    float acc = 0.0f;
#pragma unroll
    for (int i = 0; i < F4_PER_BLOCK / THREADS; ++i) {   // 16 iters, 16 B/lane each
        float4 v = xp[i * THREADS + threadIdx.x];
        acc += (v.x + v.y) + (v.z + v.w);
    }
    // wave64 shuffle reduction
#pragma unroll
    for (int off = 32; off > 0; off >>= 1)
        acc += __shfl_down(acc, off, 64);
    __shared__ float smem[THREADS / 64];
    const int lane = threadIdx.x & 63;
    const int wv   = threadIdx.x >> 6;
    if (lane == 0) smem[wv] = acc;
    __syncthreads();
    if (threadIdx.x == 0)
        part[blockIdx.x] = (smem[0] + smem[1]) + (smem[2] + smem[3]);
}

// Kernel 2: one thread per batch element. Combine the 4 partials per plane,
// fold the kernel into per-(ci,co) sums, 3x16 matvec, bias, logsumexp, x10.
__global__ __launch_bounds__(BATCH) void finalize(
        const float* __restrict__ part,
        const float* __restrict__ weight,   // (C_IN, C_OUT, 3, 3) flat
        const float* __restrict__ bias,     // (C_OUT,)
        float* __restrict__ out) {          // (BATCH,)
    __shared__ float Wsum[C_IN][C_OUT];
    __shared__ float bsh[C_OUT];
    const int t = threadIdx.x;
    if (t < C_IN * C_OUT) {
        float s = 0.0f;
#pragma unroll
        for (int k = 0; k < 9; ++k) s += weight[t * 9 + k];
        Wsum[t / C_OUT][t % C_OUT] = s;
    }
    if (t < C_OUT) bsh[t] = bias[t];
    __syncthreads();

    // per-batch channel sums of x
    float S[C_IN];
#pragma unroll
    for (int ci = 0; ci < C_IN; ++ci) {
        float s = 0.0f;
#pragma unroll
        for (int k = 0; k < BPP; ++k)
            s += part[(t * C_IN + ci) * BPP + k];
        S[ci] = s;
    }

    const float inv_area = 1.0f / (258.0f * 258.0f);
    float m[C_OUT];
    float mmax = -1e30f;
#pragma unroll
    for (int co = 0; co < C_OUT; ++co) {
        float v = (S[0] * Wsum[0][co] + S[1] * Wsum[1][co] + S[2] * Wsum[2][co])
                      * inv_area + bsh[co];
        m[co] = v;
        mmax = fmaxf(mmax, v);
    }
    float se = 0.0f;
#pragma unroll
    for (int co = 0; co < C_OUT; ++co) se += expf(m[co] - mmax);
    out[t] = 10.0f * (logf(se) + mmax);
}

extern "C" void kernel_launch(void* const* d_in, const int* in_sizes, int n_in,
                              void* d_out, int out_size, void* d_ws, size_t ws_size,
                              hipStream_t stream) {
    const float* x      = (const float*)d_in[0];
    const float* weight = (const float*)d_in[1];
    const float* bias   = (const float*)d_in[2];
    float* out  = (float*)d_out;
    float* part = (float*)d_ws;   // NBLK floats = 6 KB scratch

    plane_partials<<<NBLK, THREADS, 0, stream>>>(x, part);
    finalize<<<1, BATCH, 0, stream>>>(part, weight, bias, out);
}